// Round 4
// baseline (162.470 us; speedup 1.0000x reference)
//
#include <hip/hip_runtime.h>
#include <hip/hip_bf16.h>

#define D_DIM 256
#define TEMP 0.2f
// ZSCALE = sqrt(log2(e)/TEMP): fold 1/(T*ln2) into z so epilogue is exp2(acc)
#define ZSCALE 2.6857913f
#define TGRID 64           // N / 128 row/col tiles
#define NB 512             // blocks (2 per CU)
#define NTILES 2080        // TGRID*(TGRID+1)/2 triangular tiles

typedef __bf16 bf16x8 __attribute__((ext_vector_type(8)));
typedef float f32x4 __attribute__((ext_vector_type(4)));

typedef const __attribute__((address_space(1))) void* gptr_t;
typedef __attribute__((address_space(3))) void* lptr_t;

// ---------------- kernel 1: normalize + positives ----------------
__global__ __launch_bounds__(256) void nt_normalize(
    const float* __restrict__ ei, const float* __restrict__ ej,
    ushort* __restrict__ z, float* __restrict__ pos, int B) {
  int b = blockIdx.x;
  int d = threadIdx.x;
  float xi = ei[(size_t)b * D_DIM + d];
  float xj = ej[(size_t)b * D_DIM + d];
  float si = xi * xi, sj = xj * xj, sij = xi * xj;
  for (int off = 1; off < 64; off <<= 1) {
    si  += __shfl_xor(si, off);
    sj  += __shfl_xor(sj, off);
    sij += __shfl_xor(sij, off);
  }
  __shared__ float red[3][4];
  int wv = threadIdx.x >> 6, lane = threadIdx.x & 63;
  if (lane == 0) { red[0][wv] = si; red[1][wv] = sj; red[2][wv] = sij; }
  __syncthreads();
  si  = red[0][0] + red[0][1] + red[0][2] + red[0][3];
  sj  = red[1][0] + red[1][1] + red[1][2] + red[1][3];
  sij = red[2][0] + red[2][1] + red[2][2] + red[2][3];
  float ri = rsqrtf(si), rj = rsqrtf(sj);
  __hip_bfloat16 zi = __float2bfloat16(xi * ri * ZSCALE);
  __hip_bfloat16 zj = __float2bfloat16(xj * rj * ZSCALE);
  z[(size_t)b * D_DIM + d]       = *reinterpret_cast<ushort*>(&zi);
  z[(size_t)(B + b) * D_DIM + d] = *reinterpret_cast<ushort*>(&zj);
  if (threadIdx.x == 0) pos[b] = sij * ri * rj;
}

// ---------------- kernel 2: row-panel-resident triangular GEMM -----------
// Each block owns a flat range of triangular tiles (rt<=ct), lex order.
// A panel (128 rows x K=256) lives in REGISTERS (af[8][4], 128 VGPR/lane);
// only B (64KB) is staged per step. Single B buffer, 2 blocks/CU; next-tile
// stage issued right after the post-compute barrier so the epilogue VALU
// overlaps the in-flight loads. XOR swizzle (byte ^= (row&7)<<4) on global
// SOURCE (linear LDS dest, rule #21) and on every ds_read address.
// Slots: row-sums of (rt,ct) -> partial[2ct+wc][row];
//        col-sums (rt<ct)    -> partial[2rt+wr][col]. Exact partition of 128.
__global__ __launch_bounds__(256, 2) void nt_gemm_rowsum(
    const ushort* __restrict__ z, float* __restrict__ partial, int N) {
  // XCD-chunked remap (m204 bijective, NB%8==0): consecutive logical blocks
  // (sharing A panels) land on the same XCD's L2.
  int hw = blockIdx.x;
  int b = (hw & 7) * (NB / 8) + (hw >> 3);
  int s = (b * NTILES) / NB;
  int e = ((b + 1) * NTILES) / NB;

  // decode first tile index -> (rt, ct)
  int rem = s, rt = 0;
  while (rem >= TGRID - rt) { rem -= TGRID - rt; ++rt; }
  int ct = rt + rem;

  __shared__ __align__(16) ushort Bs[128 * 256];  // 64KB; holds A during panel load
  char* bsb = (char*)Bs;
  const char* zb = (const char*)z;  // row stride 512B

  int t = threadIdx.x, lane = t & 63, wv = t >> 6;
  int wr = wv >> 1, wc = wv & 1;

  // Stage a full 128x256 bf16 panel (64KB): 4096 16B chunks, 32 per 512B row.
  auto STAGE = [&](int panel) {
#pragma unroll
    for (int p = 0; p < 16; ++p) {
      int chunk = p * 256 + t;          // 0..4095 16B chunks
      int row = chunk >> 5;             // 32 chunks per 512B row
      int c = chunk & 31;
      int cl = c ^ (row & 7);           // inverse swizzle on SOURCE
      const char* g = zb + (size_t)(panel * 128 + row) * 512 + cl * 16;
      __builtin_amdgcn_global_load_lds((gptr_t)g, (lptr_t)(bsb + chunk * 16), 16, 0, 0);
    }
  };

  bf16x8 af[8][4];                      // A frags: [ks][m], 128 VGPR
  int cur_rt = -1;
  bool staged = false;

  for (int idx = s; idx < e; ++idx) {
    if (rt != cur_rt) {
      // (re)stage A panel into LDS, pull frags to registers
      STAGE(rt);
      __syncthreads();
#pragma unroll
      for (int ks = 0; ks < 8; ++ks)
#pragma unroll
        for (int m = 0; m < 4; ++m) {
          int r = wr * 64 + m * 16 + (lane & 15);
          int addr = ((r << 9) + ks * 64 + ((lane >> 4) << 4)) ^ ((r & 7) << 4);
          af[ks][m] = *reinterpret_cast<const bf16x8*>(bsb + addr);
        }
      __syncthreads();                  // frags in regs before overwrite
      cur_rt = rt;
      STAGE(ct);
      __syncthreads();
    } else if (!staged) {
      STAGE(ct);
      __syncthreads();
    } else {
      __syncthreads();                  // drain prefetched B stage
    }

    // ---- compute: acc = A_regs x B_lds over K=256 ----
    f32x4 acc[4][4];
#pragma unroll
    for (int m = 0; m < 4; ++m)
#pragma unroll
      for (int n = 0; n < 4; ++n) acc[m][n] = f32x4{0.f, 0.f, 0.f, 0.f};
#pragma unroll
    for (int ks = 0; ks < 8; ++ks) {
      bf16x8 bfr[4];
#pragma unroll
      for (int n = 0; n < 4; ++n) {
        int r = wc * 64 + n * 16 + (lane & 15);
        int addr = ((r << 9) + ks * 64 + ((lane >> 4) << 4)) ^ ((r & 7) << 4);
        bfr[n] = *reinterpret_cast<const bf16x8*>(bsb + addr);
      }
#pragma unroll
      for (int m = 0; m < 4; ++m)
#pragma unroll
        for (int n = 0; n < 4; ++n)
          acc[m][n] = __builtin_amdgcn_mfma_f32_16x16x32_bf16(af[ks][m], bfr[n], acc[m][n], 0, 0, 0);
    }
    int srt = rt, sct = ct;
    __syncthreads();                    // all waves done reading B buffer

    // advance + prefetch next B while epilogue runs
    ++ct;
    if (ct == TGRID) { ++rt; ct = rt; }
    staged = false;
    if (idx + 1 < e && rt == cur_rt) { STAGE(ct); staged = true; }

    // ---- epilogue (register-only): exp2, diag mask, row/col sums ----
    bool isdiag = (srt == sct);
    int rbase = srt * 128 + wr * 64;
    int cbase = sct * 128 + wc * 64 + (lane & 15);
#pragma unroll
    for (int m = 0; m < 4; ++m)
#pragma unroll
      for (int n = 0; n < 4; ++n)
#pragma unroll
        for (int j = 0; j < 4; ++j) {
          int rowg = rbase + m * 16 + (lane >> 4) * 4 + j;
          int colg = cbase + n * 16;
          float ex = exp2f(acc[m][n][j]);
          acc[m][n][j] = (isdiag && rowg == colg) ? 0.f : ex;
        }
#pragma unroll
    for (int m = 0; m < 4; ++m)
#pragma unroll
      for (int j = 0; j < 4; ++j) {
        float rs = acc[m][0][j] + acc[m][1][j] + acc[m][2][j] + acc[m][3][j];
        rs += __shfl_xor(rs, 1);
        rs += __shfl_xor(rs, 2);
        rs += __shfl_xor(rs, 4);
        rs += __shfl_xor(rs, 8);
        if ((lane & 15) == 0) {
          int rowg = rbase + m * 16 + (lane >> 4) * 4 + j;
          partial[(size_t)(2 * sct + wc) * N + rowg] = rs;
        }
      }
    if (!isdiag) {
#pragma unroll
      for (int n = 0; n < 4; ++n) {
        float cs = 0.f;
#pragma unroll
        for (int m = 0; m < 4; ++m)
#pragma unroll
          for (int j = 0; j < 4; ++j) cs += acc[m][n][j];
        cs += __shfl_xor(cs, 16);
        cs += __shfl_xor(cs, 32);
        if ((lane >> 4) == 0) {
          int colg = cbase + n * 16;
          partial[(size_t)(2 * srt + wr) * N + colg] = cs;
        }
      }
    }
  }
}

// ---------------- kernel 3: per-row finish ----------------
__global__ __launch_bounds__(256) void nt_rowfinish(
    const float* __restrict__ partial, const float* __restrict__ pos,
    float* __restrict__ rowfinal, int N, int B) {
  int r = blockIdx.x * blockDim.x + threadIdx.x;
  if (r >= N) return;
  float s = 0.f;
#pragma unroll 8
  for (int p = 0; p < 128; ++p) s += partial[(size_t)p * N + r];
  float pv = pos[r < B ? r : r - B];
  rowfinal[r] = logf(s) - pv * (1.0f / TEMP);
}

// ---------------- kernel 4: final scalar reduce ----------------
__global__ __launch_bounds__(1024) void nt_final(
    const float* __restrict__ rowfinal, float* __restrict__ out, int N) {
  float s = 0.f;
  for (int i = threadIdx.x; i < N; i += 1024) s += rowfinal[i];
  for (int off = 1; off < 64; off <<= 1) s += __shfl_xor(s, off);
  __shared__ float red[16];
  int wv = threadIdx.x >> 6, lane = threadIdx.x & 63;
  if (lane == 0) red[wv] = s;
  __syncthreads();
  if (threadIdx.x == 0) {
    float tot = 0.f;
#pragma unroll
    for (int i = 0; i < 16; ++i) tot += red[i];
    out[0] = tot / (float)N;
  }
}

extern "C" void kernel_launch(void* const* d_in, const int* in_sizes, int n_in,
                              void* d_out, int out_size, void* d_ws, size_t ws_size,
                              hipStream_t stream) {
  const float* ei = (const float*)d_in[0];
  const float* ej = (const float*)d_in[1];
  int B = in_sizes[0] / D_DIM;  // 4096
  int N = 2 * B;                // 8192

  char* ws = (char*)d_ws;
  ushort* z      = (ushort*)ws;                                   // N*256*2  = 4 MB
  float* partial = (float*)(ws + (size_t)N * D_DIM * 2);          // 128*N*4  = 4 MB
  float* pos     = (float*)(ws + (size_t)N * D_DIM * 2 + (size_t)128 * N * 4);
  float* rowfinal = pos + B;
  float* out = (float*)d_out;

  nt_normalize<<<B, 256, 0, stream>>>(ei, ej, z, pos, B);
  nt_gemm_rowsum<<<NB, 256, 0, stream>>>(z, partial, N);
  nt_rowfinish<<<(N + 255) / 256, 256, 0, stream>>>(partial, pos, rowfinal, N, B);
  nt_final<<<1, 1024, 0, stream>>>(rowfinal, out, N);
}

// Round 6
// 80.120 us; speedup vs baseline: 2.0278x; 2.0278x over previous
//
#include <hip/hip_runtime.h>
#include <hip/hip_bf16.h>

#define D_DIM 256
#define TEMP 0.2f
// ZSCALE = sqrt(log2(e)/TEMP): fold 1/(T*ln2) into z so epilogue is exp2(acc)
#define ZSCALE 2.6857913f
#define TGRID 64           // N / 128 row/col tiles
#define NBLK 256           // 1 block per CU
#define NTILES 2080        // TGRID*(TGRID+1)/2 triangular tiles

typedef __bf16 bf16x8 __attribute__((ext_vector_type(8)));
typedef float f32x4 __attribute__((ext_vector_type(4)));

typedef const __attribute__((address_space(1))) void* gptr_t;
typedef __attribute__((address_space(3))) void* lptr_t;

// ---------------- kernel 1: normalize + positives ----------------
__global__ __launch_bounds__(256) void nt_normalize(
    const float* __restrict__ ei, const float* __restrict__ ej,
    ushort* __restrict__ z, float* __restrict__ pos, int B) {
  int b = blockIdx.x;
  int d = threadIdx.x;
  float xi = ei[(size_t)b * D_DIM + d];
  float xj = ej[(size_t)b * D_DIM + d];
  float si = xi * xi, sj = xj * xj, sij = xi * xj;
  for (int off = 1; off < 64; off <<= 1) {
    si  += __shfl_xor(si, off);
    sj  += __shfl_xor(sj, off);
    sij += __shfl_xor(sij, off);
  }
  __shared__ float red[3][4];
  int wv = threadIdx.x >> 6, lane = threadIdx.x & 63;
  if (lane == 0) { red[0][wv] = si; red[1][wv] = sj; red[2][wv] = sij; }
  __syncthreads();
  si  = red[0][0] + red[0][1] + red[0][2] + red[0][3];
  sj  = red[1][0] + red[1][1] + red[1][2] + red[1][3];
  sij = red[2][0] + red[2][1] + red[2][2] + red[2][3];
  float ri = rsqrtf(si), rj = rsqrtf(sj);
  __hip_bfloat16 zi = __float2bfloat16(xi * ri * ZSCALE);
  __hip_bfloat16 zj = __float2bfloat16(xj * rj * ZSCALE);
  z[(size_t)b * D_DIM + d]       = *reinterpret_cast<ushort*>(&zi);
  z[(size_t)(B + b) * D_DIM + d] = *reinterpret_cast<ushort*>(&zj);
  if (threadIdx.x == 0) pos[b] = sij * ri * rj;
}

// ---------------- kernel 2: row-panel-resident triangular GEMM -----------
// 512 threads = 8 waves in a 2x4 grid; wave tile 64 rows x 32 cols.
// A panel (128 x K=256) in registers (af[8][4], 128 VGPR); B double-buffered
// in LDS (2 x 64KB); prefetch issued BEFORE compute so the barrier's vmcnt
// drain overlaps the MFMA phase. At a row transition the new row's first
// (diagonal) B tile IS the A panel -> one stage serves both.
// XOR swizzle (byte ^= (row&7)<<4) on global SOURCE (linear LDS dest) and on
// every ds_read address.
// partial slots (256): row-sums of (rt,ct) -> slot 4*ct+wc (each wave's 32
//   cols, rows split by lane>>4 quads);
// col-sums (rt<ct) -> slot 4*rt + 2*wr + rowhalf, written from lanes with
//   (lane>>4) even after one shfl_xor(16): rowhalf 0 = row-groups{0,1},
//   rowhalf 1 = row-groups{2,3}; 16 column-lanes x 2 n-frags = 32 cols/wave.
// Per global row r (tile-row rt): row-slots cover [4rt,256), col-slots
// [0,4rt) -- exact partition of [0,256), every (slot,r) written once.
__global__ __launch_bounds__(512, 2) void nt_gemm_rowsum(
    const ushort* __restrict__ z, float* __restrict__ partial, int N) {
  // XCD-chunked bijective remap: consecutive logical blocks (sharing A
  // panels) land on the same XCD's L2.
  int hw = blockIdx.x;
  int b = (hw & 7) * (NBLK / 8) + (hw >> 3);
  int s = (b * NTILES) / NBLK;
  int e = ((b + 1) * NTILES) / NBLK;

  // decode first tile index -> (rt, ct), lex order over ct>=rt
  int rem = s, rt = 0;
  while (rem >= TGRID - rt) { rem -= TGRID - rt; ++rt; }
  int ct = rt + rem;

  __shared__ __align__(16) ushort Bs[2][128 * 256];  // 2 x 64KB
  const char* zb = (const char*)z;  // row stride 512B

  int t = threadIdx.x, lane = t & 63, wv = t >> 6;
  int wr = wv >> 2, wc = wv & 3;    // 2 wave-rows x 4 wave-cols

  // Stage a 128x256 bf16 panel (64KB): 4096 16B chunks, 32 per 512B row.
  auto STAGE = [&](int buf, int panel) {
    char* dst = (char*)Bs + buf * 65536;
#pragma unroll
    for (int p = 0; p < 8; ++p) {
      int chunk = p * 512 + t;          // 0..4095
      int row = chunk >> 5;             // 32 chunks per 512B row
      int c = chunk & 31;
      int cl = c ^ (row & 7);           // inverse swizzle on SOURCE
      const char* g = zb + (size_t)(panel * 128 + row) * 512 + cl * 16;
      __builtin_amdgcn_global_load_lds((gptr_t)g, (lptr_t)(dst + chunk * 16), 16, 0, 0);
    }
  };

  bf16x8 af[8][4];                      // A frags [ks][m]: 64 rows, 128 VGPR
  auto READ_AF = [&](int buf) {
    const char* src = (const char*)Bs + buf * 65536;
#pragma unroll
    for (int ks = 0; ks < 8; ++ks)
#pragma unroll
      for (int m = 0; m < 4; ++m) {
        int r = wr * 64 + m * 16 + (lane & 15);
        int addr = ((r << 9) + ks * 64 + ((lane >> 4) << 4)) ^ ((r & 7) << 4);
        af[ks][m] = *reinterpret_cast<const bf16x8*>(src + addr);
      }
  };

  // init: A panel into buf0; first B into buf1 unless diagonal (==A)
  STAGE(0, rt);
  bool d0 = (ct == rt);
  if (!d0) STAGE(1, ct);
  __syncthreads();
  READ_AF(0);
  __syncthreads();                      // af reads done before buf0 reuse
  int bp = d0 ? 0 : 1;

  for (int idx = s; idx < e; ++idx) {
    bool lastrow = (ct == TGRID - 1);
    bool more = (idx + 1 < e);
    if (more) STAGE(bp ^ 1, lastrow ? (rt + 1) : (ct + 1));

    // ---- compute: acc = A_regs x B_lds over K=256 ----
    f32x4 acc[4][2];
#pragma unroll
    for (int m = 0; m < 4; ++m)
#pragma unroll
      for (int n = 0; n < 2; ++n) acc[m][n] = f32x4{0.f, 0.f, 0.f, 0.f};
    const char* cb = (const char*)Bs + bp * 65536;
#pragma unroll
    for (int ks = 0; ks < 8; ++ks) {
      bf16x8 bfr[2];
#pragma unroll
      for (int n = 0; n < 2; ++n) {
        int r = wc * 32 + n * 16 + (lane & 15);
        int addr = ((r << 9) + ks * 64 + ((lane >> 4) << 4)) ^ ((r & 7) << 4);
        bfr[n] = *reinterpret_cast<const bf16x8*>(cb + addr);
      }
#pragma unroll
      for (int m = 0; m < 4; ++m)
#pragma unroll
        for (int n = 0; n < 2; ++n)
          acc[m][n] = __builtin_amdgcn_mfma_f32_16x16x32_bf16(af[ks][m], bfr[n], acc[m][n], 0, 0, 0);
    }

    // ---- epilogue (register-only): exp2, diag mask, row/col sums ----
    bool isdiag = (rt == ct);
    int rbase = rt * 128 + wr * 64;
    int cbase = ct * 128 + wc * 32 + (lane & 15);
#pragma unroll
    for (int m = 0; m < 4; ++m)
#pragma unroll
      for (int n = 0; n < 2; ++n)
#pragma unroll
        for (int j = 0; j < 4; ++j) {
          int rowg = rbase + m * 16 + (lane >> 4) * 4 + j;
          int colg = cbase + n * 16;
          float ex = exp2f(acc[m][n][j]);
          acc[m][n][j] = (isdiag && rowg == colg) ? 0.f : ex;
        }
    // row sums -> slot 4*ct + wc
#pragma unroll
    for (int m = 0; m < 4; ++m)
#pragma unroll
      for (int j = 0; j < 4; ++j) {
        float rs = acc[m][0][j] + acc[m][1][j];
        rs += __shfl_xor(rs, 1);
        rs += __shfl_xor(rs, 2);
        rs += __shfl_xor(rs, 4);
        rs += __shfl_xor(rs, 8);
        if ((lane & 15) == 0) {
          int rowg = rbase + m * 16 + (lane >> 4) * 4 + j;
          partial[(size_t)(4 * ct + wc) * N + rowg] = rs;
        }
      }
    // col sums -> slots 4*rt + 2*wr + rowhalf; all 16 column-lanes write
    if (!isdiag) {
#pragma unroll
      for (int n = 0; n < 2; ++n) {
        float cs = 0.f;
#pragma unroll
        for (int m = 0; m < 4; ++m)
#pragma unroll
          for (int j = 0; j < 4; ++j) cs += acc[m][n][j];
        cs += __shfl_xor(cs, 16);      // combine row-groups {0,1} and {2,3}
        int g = lane >> 4;             // 0..3
        if ((g & 1) == 0) {            // lanes 0-15 (half 0), 32-47 (half 1)
          int colg = cbase + n * 16;   // cbase carries lane&15: 16 columns
          int slot = 4 * rt + 2 * wr + (g >> 1);
          partial[(size_t)slot * N + colg] = cs;
        }
      }
    }
    __syncthreads();                    // prefetch landed; bp free to flip

    if (more) {
      if (!lastrow) { ++ct; bp ^= 1; }
      else {
        ++rt; ct = rt;                  // next tile is the diagonal
        READ_AF(bp ^ 1);                // new A panel (also serves as its B)
        bp ^= 1;                        // next prefetch hits the old buffer
      }
    }
  }
}

// ---------------- kernel 3: per-row finish ----------------
__global__ __launch_bounds__(256) void nt_rowfinish(
    const float* __restrict__ partial, const float* __restrict__ pos,
    float* __restrict__ rowfinal, int N, int B) {
  int r = blockIdx.x * blockDim.x + threadIdx.x;
  if (r >= N) return;
  float s = 0.f;
#pragma unroll 8
  for (int p = 0; p < 256; ++p) s += partial[(size_t)p * N + r];
  float pv = pos[r < B ? r : r - B];
  rowfinal[r] = logf(s) - pv * (1.0f / TEMP);
}

// ---------------- kernel 4: final scalar reduce ----------------
__global__ __launch_bounds__(1024) void nt_final(
    const float* __restrict__ rowfinal, float* __restrict__ out, int N) {
  float s = 0.f;
  for (int i = threadIdx.x; i < N; i += 1024) s += rowfinal[i];
  for (int off = 1; off < 64; off <<= 1) s += __shfl_xor(s, off);
  __shared__ float red[16];
  int wv = threadIdx.x >> 6, lane = threadIdx.x & 63;
  if (lane == 0) red[wv] = s;
  __syncthreads();
  if (threadIdx.x == 0) {
    float tot = 0.f;
#pragma unroll
    for (int i = 0; i < 16; ++i) tot += red[i];
    out[0] = tot / (float)N;
  }
}

extern "C" void kernel_launch(void* const* d_in, const int* in_sizes, int n_in,
                              void* d_out, int out_size, void* d_ws, size_t ws_size,
                              hipStream_t stream) {
  const float* ei = (const float*)d_in[0];
  const float* ej = (const float*)d_in[1];
  int B = in_sizes[0] / D_DIM;  // 4096
  int N = 2 * B;                // 8192

  char* ws = (char*)d_ws;
  ushort* z      = (ushort*)ws;                                   // 4 MB
  float* partial = (float*)(ws + (size_t)N * D_DIM * 2);          // 256*N*4 = 8 MB
  float* pos     = (float*)(ws + (size_t)N * D_DIM * 2 + (size_t)256 * N * 4);
  float* rowfinal = pos + B;
  float* out = (float*)d_out;

  nt_normalize<<<B, 256, 0, stream>>>(ei, ej, z, pos, B);
  nt_gemm_rowsum<<<NBLK, 512, 0, stream>>>(z, partial, N);
  nt_rowfinish<<<(N + 255) / 256, 256, 0, stream>>>(partial, pos, rowfinal, N, B);
  nt_final<<<1, 1024, 0, stream>>>(rowfinal, out, N);
}

// Round 7
// 64.896 us; speedup vs baseline: 2.5035x; 1.2346x over previous
//
#include <hip/hip_runtime.h>
#include <hip/hip_bf16.h>

#define D_DIM 256
#define TEMP 0.2f
// ZSCALE = sqrt(log2(e)/TEMP): fold 1/(T*ln2) into z so epilogue is exp2(acc)
#define ZSCALE 2.6857913f
#define TGRID 64           // N / 128 row/col tiles
#define NBLK 256           // 1 block per CU
#define NTILES 2080        // TGRID*(TGRID+1)/2 triangular tiles

typedef float f32x4 __attribute__((ext_vector_type(4)));

typedef const __attribute__((address_space(1))) void* gptr_t;
typedef __attribute__((address_space(3))) void* lptr_t;

// ---------------- kernel 1: normalize + positives -> fp8 e4m3 ----------------
__global__ __launch_bounds__(256) void nt_normalize(
    const float* __restrict__ ei, const float* __restrict__ ej,
    unsigned char* __restrict__ z8, float* __restrict__ pos, int B) {
  int b = blockIdx.x;
  int d = threadIdx.x;
  float xi = ei[(size_t)b * D_DIM + d];
  float xj = ej[(size_t)b * D_DIM + d];
  float si = xi * xi, sj = xj * xj, sij = xi * xj;
  for (int off = 1; off < 64; off <<= 1) {
    si  += __shfl_xor(si, off);
    sj  += __shfl_xor(sj, off);
    sij += __shfl_xor(sij, off);
  }
  __shared__ float red[3][4];
  int wv = threadIdx.x >> 6, lane = threadIdx.x & 63;
  if (lane == 0) { red[0][wv] = si; red[1][wv] = sj; red[2][wv] = sij; }
  __syncthreads();
  si  = red[0][0] + red[0][1] + red[0][2] + red[0][3];
  sj  = red[1][0] + red[1][1] + red[1][2] + red[1][3];
  sij = red[2][0] + red[2][1] + red[2][2] + red[2][3];
  float ri = rsqrtf(si), rj = rsqrtf(sj);
  float zif = xi * ri * ZSCALE;
  float zjf = xj * rj * ZSCALE;
  // pack pairs (d, d+1) into one ushort of 2 fp8 bytes (HW RNE, OCP e4m3)
  float zih = __shfl_down(zif, 1);
  float zjh = __shfl_down(zjf, 1);
  if ((d & 1) == 0) {
    int pki = __builtin_amdgcn_cvt_pk_fp8_f32(zif, zih, 0, false);
    int pkj = __builtin_amdgcn_cvt_pk_fp8_f32(zjf, zjh, 0, false);
    ushort* zi_row = (ushort*)(z8 + (size_t)b * D_DIM);
    ushort* zj_row = (ushort*)(z8 + (size_t)(B + b) * D_DIM);
    zi_row[d >> 1] = (ushort)(pki & 0xffff);
    zj_row[d >> 1] = (ushort)(pkj & 0xffff);
  }
  if (threadIdx.x == 0) pos[b] = sij * ri * rj;
}

// ---------------- kernel 2: row-panel-resident triangular GEMM (fp8) --------
// 512 threads = 8 waves (2 wave-rows x 4 wave-cols); wave tile 64 rows x 32
// cols. A panel (128 x K=256 fp8) in registers: af[8][4] ulong = 64 VGPR;
// acc 32 (AGPR), bfr 4 -> arch demand ~110, fits the 128-arch split cleanly.
// B single-prefetch double buffer (2 x 32KB LDS); stage issued BEFORE compute.
// XOR swizzle (byte ^= (row&7)<<4): applied to the 16B-chunk index on the
// global SOURCE (LDS dest linear, rule #21) and to every ds_read address.
// Per tile, per-wave row/col sums are combined across waves in LDS -> only 64
// partial slots: row-part of (rt,ct) -> partial[ct*N + rt*128 + r];
// col-part (rt<ct) -> partial[rt*N + ct*128 + c]. For any global row with
// tile-row rt: slots [rt,64) from row-parts, [0,rt) from col-parts of (rt',rt)
// -> exact partition of [0,64), each written exactly once.
__global__ __launch_bounds__(512, 2) void nt_gemm_rowsum(
    const unsigned char* __restrict__ z8, float* __restrict__ partial, int N) {
  // XCD-chunked bijective remap: consecutive logical blocks (sharing panels)
  // land on the same XCD's L2.
  int hw = blockIdx.x;
  int b = (hw & 7) * (NBLK / 8) + (hw >> 3);
  int s = (b * NTILES) / NBLK;
  int e = ((b + 1) * NTILES) / NBLK;

  // decode first tile index -> (rt, ct), lex order over ct>=rt
  int rem = s, rt = 0;
  while (rem >= TGRID - rt) { rem -= TGRID - rt; ++rt; }
  int ct = rt + rem;

  __shared__ __align__(16) unsigned char Bs[2][128 * 256];  // 2 x 32KB fp8
  __shared__ float red_r[4][128];   // per-wave-col row sums
  __shared__ float red_c[4][128];   // per (wave-row, half) col sums

  int t = threadIdx.x, lane = t & 63, wv = t >> 6;
  int wr = wv >> 2, wc = wv & 3;    // 2 wave-rows x 4 wave-cols

  // Stage a 128x256 fp8 panel (32KB): 2048 16B chunks, 16 per 256B row.
  auto STAGE = [&](int buf, int panel) {
    char* dst = (char*)Bs[buf];
#pragma unroll
    for (int p = 0; p < 4; ++p) {
      int chunk = p * 512 + t;          // 0..2047
      int row = chunk >> 4;             // 16 chunks per 256B row
      int c = chunk & 15;
      int cl = c ^ (row & 7);           // inverse swizzle on SOURCE
      const char* g = (const char*)z8 + (size_t)(panel * 128 + row) * 256 + cl * 16;
      __builtin_amdgcn_global_load_lds((gptr_t)g, (lptr_t)(dst + chunk * 16), 16, 0, 0);
    }
  };

  unsigned long af[8][4];               // A frags [ks][m]: 64 rows x K=256, 64 VGPR
  auto READ_AF = [&](int buf) {
    const char* src = (const char*)Bs[buf];
#pragma unroll
    for (int ks = 0; ks < 8; ++ks)
#pragma unroll
      for (int m = 0; m < 4; ++m) {
        int r = wr * 64 + m * 16 + (lane & 15);
        int addr = ((r << 8) + ks * 32 + ((lane >> 4) << 3)) ^ ((r & 7) << 4);
        af[ks][m] = *reinterpret_cast<const unsigned long*>(src + addr);
      }
  };

  // init: A panel into buf0; first B into buf1 unless diagonal (==A)
  STAGE(0, rt);
  bool d0 = (ct == rt);
  if (!d0) STAGE(1, ct);
  __syncthreads();
  READ_AF(0);
  __syncthreads();                      // af reads done before buf0 reuse
  int bp = d0 ? 0 : 1;

  for (int idx = s; idx < e; ++idx) {
    bool lastrow = (ct == TGRID - 1);
    bool more = (idx + 1 < e);
    if (more) STAGE(bp ^ 1, lastrow ? (rt + 1) : (ct + 1));

    // ---- compute: acc = A_regs x B_lds over K=256 ----
    f32x4 acc[4][2];
#pragma unroll
    for (int m = 0; m < 4; ++m)
#pragma unroll
      for (int n = 0; n < 2; ++n) acc[m][n] = f32x4{0.f, 0.f, 0.f, 0.f};
    const char* cb = (const char*)Bs[bp];
#pragma unroll
    for (int ks = 0; ks < 8; ++ks) {
      unsigned long bfr[2];
#pragma unroll
      for (int n = 0; n < 2; ++n) {
        int r = wc * 32 + n * 16 + (lane & 15);
        int addr = ((r << 8) + ks * 32 + ((lane >> 4) << 3)) ^ ((r & 7) << 4);
        bfr[n] = *reinterpret_cast<const unsigned long*>(cb + addr);
      }
#pragma unroll
      for (int m = 0; m < 4; ++m)
#pragma unroll
        for (int n = 0; n < 2; ++n)
          acc[m][n] = __builtin_amdgcn_mfma_f32_16x16x32_fp8_fp8(
              (long)af[ks][m], (long)bfr[n], acc[m][n], 0, 0, 0);
    }

    // ---- epilogue: exp2, diag mask, per-wave sums -> LDS ----
    bool isdiag = (rt == ct);
    int rbase = rt * 128 + wr * 64;
    int cbase = ct * 128 + wc * 32 + (lane & 15);
#pragma unroll
    for (int m = 0; m < 4; ++m)
#pragma unroll
      for (int n = 0; n < 2; ++n)
#pragma unroll
        for (int j = 0; j < 4; ++j) {
          int rowg = rbase + m * 16 + (lane >> 4) * 4 + j;
          int colg = cbase + n * 16;
          float ex = exp2f(acc[m][n][j]);
          acc[m][n][j] = (isdiag && rowg == colg) ? 0.f : ex;
        }
    // per-wave row sums -> red_r[wc][tile row]
#pragma unroll
    for (int m = 0; m < 4; ++m)
#pragma unroll
      for (int j = 0; j < 4; ++j) {
        float rs = acc[m][0][j] + acc[m][1][j];
        rs += __shfl_xor(rs, 1);
        rs += __shfl_xor(rs, 2);
        rs += __shfl_xor(rs, 4);
        rs += __shfl_xor(rs, 8);
        if ((lane & 15) == 0)
          red_r[wc][wr * 64 + m * 16 + (lane >> 4) * 4 + j] = rs;
      }
    // per-wave col sums -> red_c[wr*2+half][tile col]
    if (!isdiag) {
#pragma unroll
      for (int n = 0; n < 2; ++n) {
        float cs = 0.f;
#pragma unroll
        for (int m = 0; m < 4; ++m)
#pragma unroll
          for (int j = 0; j < 4; ++j) cs += acc[m][n][j];
        cs += __shfl_xor(cs, 16);      // row-groups {0,1} and {2,3}
        int g = lane >> 4;
        if ((g & 1) == 0)              // lanes 0-15 (half 0), 32-47 (half 1)
          red_c[wr * 2 + (g >> 1)][wc * 32 + n * 16 + (lane & 15)] = cs;
      }
    }
    __syncthreads();                    // red_* complete; prefetch landed

    // ---- cross-wave combine -> global partial (slots: row=ct, col=rt) ----
    if (t < 128) {
      float v = red_r[0][t] + red_r[1][t] + red_r[2][t] + red_r[3][t];
      partial[(size_t)ct * N + rt * 128 + t] = v;
    } else if (t < 256 && !isdiag) {
      int c = t - 128;
      float v = red_c[0][c] + red_c[1][c] + red_c[2][c] + red_c[3][c];
      partial[(size_t)rt * N + ct * 128 + c] = v;
    }

    if (more) {
      if (!lastrow) { ++ct; bp ^= 1; }
      else {
        ++rt; ct = rt;                  // next tile is the diagonal
        READ_AF(bp ^ 1);                // new A panel (also serves as its B)
        bp ^= 1;                        // next prefetch hits the old buffer
      }
    }
    __syncthreads();                    // combine reads done before red_* reuse
  }
}

// ---------------- kernel 3: per-row finish + per-block sum ----------------
__global__ __launch_bounds__(256) void nt_rowfinish(
    const float* __restrict__ partial, const float* __restrict__ pos,
    float* __restrict__ blocksum, int N, int B) {
  int r = blockIdx.x * 256 + threadIdx.x;
  float s = 0.f;
#pragma unroll 8
  for (int p = 0; p < 64; ++p) s += partial[(size_t)p * N + r];
  float pv = pos[r < B ? r : r - B];
  float lr = logf(s) - pv * (1.0f / TEMP);
  // block reduction
  for (int off = 1; off < 64; off <<= 1) lr += __shfl_xor(lr, off);
  __shared__ float red[4];
  int wv = threadIdx.x >> 6, lane = threadIdx.x & 63;
  if (lane == 0) red[wv] = lr;
  __syncthreads();
  if (threadIdx.x == 0)
    blocksum[blockIdx.x] = red[0] + red[1] + red[2] + red[3];
}

// ---------------- kernel 4: final scalar reduce (32 values) ----------------
__global__ __launch_bounds__(64) void nt_final(
    const float* __restrict__ blocksum, float* __restrict__ out, int N) {
  int lane = threadIdx.x;
  float s = (lane < 32) ? blocksum[lane] : 0.f;
  for (int off = 1; off < 32; off <<= 1) s += __shfl_xor(s, off);
  if (lane == 0) out[0] = s / (float)N;
}

extern "C" void kernel_launch(void* const* d_in, const int* in_sizes, int n_in,
                              void* d_out, int out_size, void* d_ws, size_t ws_size,
                              hipStream_t stream) {
  const float* ei = (const float*)d_in[0];
  const float* ej = (const float*)d_in[1];
  int B = in_sizes[0] / D_DIM;  // 4096
  int N = 2 * B;                // 8192

  char* ws = (char*)d_ws;
  unsigned char* z8 = (unsigned char*)ws;                         // N*256 = 2 MB
  float* partial  = (float*)(ws + (size_t)N * D_DIM);             // 64*N*4 = 2 MB
  float* pos      = (float*)(ws + (size_t)N * D_DIM + (size_t)64 * N * 4);
  float* blocksum = pos + B;
  float* out = (float*)d_out;

  nt_normalize<<<B, 256, 0, stream>>>(ei, ej, z8, pos, B);
  nt_gemm_rowsum<<<NBLK, 512, 0, stream>>>(z8, partial, N);
  nt_rowfinish<<<N / 256, 256, 0, stream>>>(partial, pos, blocksum, N, B);
  nt_final<<<1, 64, 0, stream>>>(blocksum, out, N);
}